// Round 1
// baseline (2453.768 us; speedup 1.0000x reference)
//
#include <hip/hip_runtime.h>

#define NNODES 65536
#define FIN 1024
#define NEDGES 2097152
#define NB 64

// ---------------- init: zero agg buffers, deg = 1.0 (self-loop) ----------------
__global__ __launch_bounds__(256) void kinit(float* __restrict__ agg1, float* __restrict__ agg2,
                                             float* __restrict__ agg3, float* __restrict__ deg) {
  int i = blockIdx.x * 256 + threadIdx.x;  // [0, N*16)
  agg1[i] = 0.f;
  if (i < NNODES * 4) agg2[i] = 0.f;
  if (i < NNODES) { agg3[i] = 0.f; deg[i] = 1.0f; }
}

// ---------------- deg[dst] += ew ----------------
__global__ __launch_bounds__(256) void kdeg(const int* __restrict__ dst, const float* __restrict__ ew,
                                            float* __restrict__ deg) {
  int e = blockIdx.x * 256 + threadIdx.x;
  atomicAdd(&deg[dst[e]], ew[e]);
}

// ---------------- dinv = rsqrt(deg), in place ----------------
__global__ __launch_bounds__(256) void kdinv(float* __restrict__ deg) {
  int n = blockIdx.x * 256 + threadIdx.x;
  deg[n] = rsqrtf(deg[n]);
}

// ---------------- h1 = x @ W1  (65536x1024 @ 1024x16) ----------------
// block = 256 thr = 4 waves; block handles 64 rows; wave w covers k-quarter w.
// W1 accessed uniformly (readfirstlane) -> scalar loads + SGPR-operand FMAs.
__global__ __launch_bounds__(256) void kgemm1(const float* __restrict__ x, const float* __restrict__ W1,
                                              float* __restrict__ h1) {
  __shared__ float sdata[4][64][16];
  const int tid = threadIdx.x;
  const int w = tid >> 6;
  const int l = tid & 63;
  const int row = blockIdx.x * 64 + l;
  const int wq = __builtin_amdgcn_readfirstlane(w);
  const float4* __restrict__ xr = (const float4*)(x + (size_t)row * FIN + (size_t)wq * 256);
  const float* __restrict__ Wq = W1 + (size_t)wq * 256 * 16;

  float acc[16];
#pragma unroll
  for (int j = 0; j < 16; ++j) acc[j] = 0.f;

  for (int k16 = 0; k16 < 16; ++k16) {
#pragma unroll
    for (int u = 0; u < 4; ++u) {            // 4 consecutive float4 = one 64B line/lane
      const int k4 = k16 * 4 + u;
      float4 xv = xr[k4];
      const float xs[4] = {xv.x, xv.y, xv.z, xv.w};
#pragma unroll
      for (int i = 0; i < 4; ++i) {
        const float* __restrict__ wr = Wq + (k4 * 4 + i) * 16;
#pragma unroll
        for (int j = 0; j < 16; ++j) acc[j] = fmaf(xs[i], wr[j], acc[j]);
      }
    }
  }

#pragma unroll
  for (int j = 0; j < 16; ++j) sdata[w][l][j] = acc[j];
  __syncthreads();

  const int r = tid >> 2;
  const int jg = (tid & 3) * 4;
  float4 o;
  o.x = sdata[0][r][jg + 0] + sdata[1][r][jg + 0] + sdata[2][r][jg + 0] + sdata[3][r][jg + 0];
  o.y = sdata[0][r][jg + 1] + sdata[1][r][jg + 1] + sdata[2][r][jg + 1] + sdata[3][r][jg + 1];
  o.z = sdata[0][r][jg + 2] + sdata[1][r][jg + 2] + sdata[2][r][jg + 2] + sdata[3][r][jg + 2];
  o.w = sdata[0][r][jg + 3] + sdata[1][r][jg + 3] + sdata[2][r][jg + 3] + sdata[3][r][jg + 3];
  *(float4*)(h1 + ((size_t)blockIdx.x * 64 + r) * 16 + jg) = o;
}

// ---------------- edge scatter: agg[dst] += h[src] * norm, F=16/4/1 ----------------
__global__ __launch_bounds__(256) void kagg16(const float* __restrict__ h, const int* __restrict__ src,
                                              const int* __restrict__ dst, const float* __restrict__ ew,
                                              const float* __restrict__ dinv, float* __restrict__ agg) {
  int e = blockIdx.x * 256 + threadIdx.x;
  int s = src[e], d = dst[e];
  float nrm = dinv[s] * ew[e] * dinv[d];
  const float4* __restrict__ hs = (const float4*)(h + (size_t)s * 16);
  float* ad = agg + (size_t)d * 16;
#pragma unroll
  for (int q = 0; q < 4; ++q) {
    float4 v = hs[q];
    atomicAdd(ad + q * 4 + 0, v.x * nrm);
    atomicAdd(ad + q * 4 + 1, v.y * nrm);
    atomicAdd(ad + q * 4 + 2, v.z * nrm);
    atomicAdd(ad + q * 4 + 3, v.w * nrm);
  }
}

__global__ __launch_bounds__(256) void kagg4(const float* __restrict__ h, const int* __restrict__ src,
                                             const int* __restrict__ dst, const float* __restrict__ ew,
                                             const float* __restrict__ dinv, float* __restrict__ agg) {
  int e = blockIdx.x * 256 + threadIdx.x;
  int s = src[e], d = dst[e];
  float nrm = dinv[s] * ew[e] * dinv[d];
  float4 v = *(const float4*)(h + (size_t)s * 4);
  float* ad = agg + (size_t)d * 4;
  atomicAdd(ad + 0, v.x * nrm);
  atomicAdd(ad + 1, v.y * nrm);
  atomicAdd(ad + 2, v.z * nrm);
  atomicAdd(ad + 3, v.w * nrm);
}

__global__ __launch_bounds__(256) void kagg1(const float* __restrict__ h, const int* __restrict__ src,
                                             const int* __restrict__ dst, const float* __restrict__ ew,
                                             const float* __restrict__ dinv, float* __restrict__ agg) {
  int e = blockIdx.x * 256 + threadIdx.x;
  int s = src[e], d = dst[e];
  float nrm = dinv[s] * ew[e] * dinv[d];
  atomicAdd(&agg[d], h[s] * nrm);
}

// ---------------- layer2: h2 = relu(agg1 + h1*dinv^2 + b1) @ W2 ----------------
__global__ __launch_bounds__(256) void klayer2(const float* __restrict__ h1, const float* __restrict__ agg1,
                                               const float* __restrict__ dinv, const float* __restrict__ W2,
                                               const float* __restrict__ b1, float* __restrict__ h2) {
  int n = blockIdx.x * 256 + threadIdx.x;
  float sn = dinv[n]; sn *= sn;
  float acc0 = 0.f, acc1 = 0.f, acc2 = 0.f, acc3 = 0.f;
#pragma unroll
  for (int q = 0; q < 4; ++q) {
    float4 av = ((const float4*)(agg1 + (size_t)n * 16))[q];
    float4 hv = ((const float4*)(h1 + (size_t)n * 16))[q];
    const float a[4] = {av.x, av.y, av.z, av.w};
    const float hh[4] = {hv.x, hv.y, hv.z, hv.w};
#pragma unroll
    for (int c = 0; c < 4; ++c) {
      int j = q * 4 + c;
      float t = a[c] + hh[c] * sn + b1[j];
      t = t > 0.f ? t : 0.f;
      acc0 = fmaf(t, W2[j * 4 + 0], acc0);
      acc1 = fmaf(t, W2[j * 4 + 1], acc1);
      acc2 = fmaf(t, W2[j * 4 + 2], acc2);
      acc3 = fmaf(t, W2[j * 4 + 3], acc3);
    }
  }
  float4 o = make_float4(acc0, acc1, acc2, acc3);
  *(float4*)(h2 + (size_t)n * 4) = o;
}

// ---------------- layer3: h3 = relu(agg2 + h2*dinv^2 + b2) @ W3 ----------------
__global__ __launch_bounds__(256) void klayer3(const float* __restrict__ h2, const float* __restrict__ agg2,
                                               const float* __restrict__ dinv, const float* __restrict__ W3,
                                               const float* __restrict__ b2, float* __restrict__ h3) {
  int n = blockIdx.x * 256 + threadIdx.x;
  float sn = dinv[n]; sn *= sn;
  float4 av = *(const float4*)(agg2 + (size_t)n * 4);
  float4 hv = *(const float4*)(h2 + (size_t)n * 4);
  const float a[4] = {av.x, av.y, av.z, av.w};
  const float hh[4] = {hv.x, hv.y, hv.z, hv.w};
  float s = 0.f;
#pragma unroll
  for (int j = 0; j < 4; ++j) {
    float t = a[j] + hh[j] * sn + b2[j];
    t = t > 0.f ? t : 0.f;
    s = fmaf(t, W3[j], s);
  }
  h3[n] = s;
}

// ---------------- flat = relu(agg3 + h3*dinv^2 + b3) ----------------
__global__ __launch_bounds__(256) void kflat(const float* __restrict__ h3, const float* __restrict__ agg3,
                                             const float* __restrict__ dinv, const float* __restrict__ b3,
                                             float* __restrict__ flat) {
  int n = blockIdx.x * 256 + threadIdx.x;
  float sn = dinv[n]; sn *= sn;
  float t = agg3[n] + h3[n] * sn + b3[0];
  flat[n] = t > 0.f ? t : 0.f;
}

// ---------------- out[b] = dot(flat, W_out[b,:]) + b_out[b] ----------------
__global__ __launch_bounds__(256) void kfinal(const float* __restrict__ flat, const float* __restrict__ Wout,
                                              const float* __restrict__ bout, float* __restrict__ out) {
  int b = blockIdx.x;
  const float4* __restrict__ f4 = (const float4*)flat;
  const float4* __restrict__ w4 = (const float4*)(Wout + (size_t)b * NNODES);
  float s = 0.f;
  for (int i = threadIdx.x; i < NNODES / 4; i += 256) {
    float4 a = f4[i];
    float4 wv = w4[i];
    s += a.x * wv.x + a.y * wv.y + a.z * wv.z + a.w * wv.w;
  }
#pragma unroll
  for (int off = 32; off; off >>= 1) s += __shfl_down(s, off, 64);
  __shared__ float red[4];
  if ((threadIdx.x & 63) == 0) red[threadIdx.x >> 6] = s;
  __syncthreads();
  if (threadIdx.x == 0) out[b] = red[0] + red[1] + red[2] + red[3] + bout[b];
}

extern "C" void kernel_launch(void* const* d_in, const int* in_sizes, int n_in,
                              void* d_out, int out_size, void* d_ws, size_t ws_size,
                              hipStream_t stream) {
  const float* x   = (const float*)d_in[0];
  const int*   A   = (const int*)d_in[1];
  const float* ew  = (const float*)d_in[2];
  const float* W1  = (const float*)d_in[3];
  const float* b1  = (const float*)d_in[4];
  const float* W2  = (const float*)d_in[5];
  const float* b2  = (const float*)d_in[6];
  const float* W3  = (const float*)d_in[7];
  const float* b3  = (const float*)d_in[8];
  const float* Wo  = (const float*)d_in[9];
  const float* bo  = (const float*)d_in[10];
  float* out = (float*)d_out;

  float* ws   = (float*)d_ws;
  float* dinv = ws;                              // N
  float* h1   = dinv + NNODES;                   // N*16
  float* agg1 = h1 + (size_t)NNODES * 16;        // N*16
  float* h2   = agg1 + (size_t)NNODES * 16;      // N*4
  float* agg2 = h2 + (size_t)NNODES * 4;         // N*4
  float* h3   = agg2 + (size_t)NNODES * 4;       // N
  float* agg3 = h3 + NNODES;                     // N
  float* flat = agg3 + NNODES;                   // N

  const int* src = A;
  const int* dst = A + NEDGES;

  kinit<<<NNODES * 16 / 256, 256, 0, stream>>>(agg1, agg2, agg3, dinv);
  kdeg<<<NEDGES / 256, 256, 0, stream>>>(dst, ew, dinv);
  kdinv<<<NNODES / 256, 256, 0, stream>>>(dinv);
  kgemm1<<<NNODES / 64, 256, 0, stream>>>(x, W1, h1);
  kagg16<<<NEDGES / 256, 256, 0, stream>>>(h1, src, dst, ew, dinv, agg1);
  klayer2<<<NNODES / 256, 256, 0, stream>>>(h1, agg1, dinv, W2, b1, h2);
  kagg4<<<NEDGES / 256, 256, 0, stream>>>(h2, src, dst, ew, dinv, agg2);
  klayer3<<<NNODES / 256, 256, 0, stream>>>(h2, agg2, dinv, W3, b2, h3);
  kagg1<<<NEDGES / 256, 256, 0, stream>>>(h3, src, dst, ew, dinv, agg3);
  kflat<<<NNODES / 256, 256, 0, stream>>>(h3, agg3, dinv, b3, flat);
  kfinal<<<NB, 256, 0, stream>>>(flat, Wo, bo, out);
}

// Round 2
// 461.929 us; speedup vs baseline: 5.3120x; 5.3120x over previous
//
#include <hip/hip_runtime.h>

#define NNODES 65536
#define FIN 1024
#define NEDGES 2097152
#define NB 64

// ================= CSR build =================

__global__ __launch_bounds__(256) void kzerocnt(int* __restrict__ cnt) {
  cnt[blockIdx.x * 256 + threadIdx.x] = 0;
}

__global__ __launch_bounds__(256) void kcount(const int* __restrict__ dst, int* __restrict__ cnt) {
  int e = blockIdx.x * 256 + threadIdx.x;
  atomicAdd(&cnt[dst[e]], 1);
}

// per-block inclusive scan (Hillis-Steele over 256) -> exclusive within block + block sums
__global__ __launch_bounds__(256) void kscan1(const int* __restrict__ cnt, int* __restrict__ rs,
                                              int* __restrict__ bsum) {
  __shared__ int sh[256];
  const int t = threadIdx.x;
  const int i = blockIdx.x * 256 + t;
  const int v = cnt[i];
  sh[t] = v;
  __syncthreads();
#pragma unroll
  for (int off = 1; off < 256; off <<= 1) {
    int add = (t >= off) ? sh[t - off] : 0;
    __syncthreads();
    sh[t] += add;
    __syncthreads();
  }
  rs[i] = sh[t] - v;                    // exclusive within block
  if (t == 255) bsum[blockIdx.x] = sh[255];
}

__global__ __launch_bounds__(256) void kscan2(const int* __restrict__ bsum, int* __restrict__ boff) {
  __shared__ int sh[256];
  const int t = threadIdx.x;
  const int v = bsum[t];
  sh[t] = v;
  __syncthreads();
#pragma unroll
  for (int off = 1; off < 256; off <<= 1) {
    int add = (t >= off) ? sh[t - off] : 0;
    __syncthreads();
    sh[t] += add;
    __syncthreads();
  }
  boff[t] = sh[t] - v;                  // exclusive block offsets
}

__global__ __launch_bounds__(256) void kscan3(int* __restrict__ rs, const int* __restrict__ boff,
                                              int* __restrict__ cursor) {
  const int i = blockIdx.x * 256 + threadIdx.x;
  const int v = rs[i] + boff[blockIdx.x];
  rs[i] = v;
  cursor[i] = v;
}

__global__ __launch_bounds__(256) void kscatter(const int* __restrict__ src, const int* __restrict__ dst,
                                                const float* __restrict__ ew, int* __restrict__ cursor,
                                                int* __restrict__ csr_src, float* __restrict__ csr_w) {
  int e = blockIdx.x * 256 + threadIdx.x;
  int d = dst[e];
  int pos = atomicAdd(&cursor[d], 1);
  csr_src[pos] = src[e];
  csr_w[pos] = ew[e];
}

// deg[n] = 1 + sum(csr_w over row n); dinv = rsqrt — wave per node
__global__ __launch_bounds__(256) void kdeg(const int* __restrict__ rs, const int* __restrict__ cnt,
                                            const float* __restrict__ csr_w, float* __restrict__ dinv) {
  const int tid = threadIdx.x, wv = tid >> 6, l = tid & 63;
  const int n = blockIdx.x * 4 + wv;
  const int beg = rs[n], len = cnt[n];
  float s = 0.f;
  for (int j = l; j < len; j += 64) s += csr_w[beg + j];
#pragma unroll
  for (int off = 1; off < 64; off <<= 1) s += __shfl_xor(s, off, 64);
  if (l == 0) dinv[n] = rsqrtf(1.0f + s);
}

// csr_w[j] *= dinv[csr_src[j]]  (fold source-side norm in once, reused 3x)
__global__ __launch_bounds__(256) void kwnorm(const int* __restrict__ csr_src, const float* __restrict__ dinv,
                                              float* __restrict__ csr_w) {
  int j = blockIdx.x * 256 + threadIdx.x;
  csr_w[j] *= dinv[csr_src[j]];
}

// ================= h1 = x @ W1  (65536x1024 @ 1024x16) =================
__global__ __launch_bounds__(256) void kgemm1(const float* __restrict__ x, const float* __restrict__ W1,
                                              float* __restrict__ h1) {
  __shared__ float sdata[4][64][16];
  const int tid = threadIdx.x;
  const int w = tid >> 6;
  const int l = tid & 63;
  const int row = blockIdx.x * 64 + l;
  const int wq = __builtin_amdgcn_readfirstlane(w);
  const float4* __restrict__ xr = (const float4*)(x + (size_t)row * FIN + (size_t)wq * 256);
  const float* __restrict__ Wq = W1 + (size_t)wq * 256 * 16;

  float acc[16];
#pragma unroll
  for (int j = 0; j < 16; ++j) acc[j] = 0.f;

  for (int k16 = 0; k16 < 16; ++k16) {
#pragma unroll
    for (int u = 0; u < 4; ++u) {
      const int k4 = k16 * 4 + u;
      float4 xv = xr[k4];
      const float xs[4] = {xv.x, xv.y, xv.z, xv.w};
#pragma unroll
      for (int i = 0; i < 4; ++i) {
        const float* __restrict__ wr = Wq + (k4 * 4 + i) * 16;
#pragma unroll
        for (int j = 0; j < 16; ++j) acc[j] = fmaf(xs[i], wr[j], acc[j]);
      }
    }
  }

#pragma unroll
  for (int j = 0; j < 16; ++j) sdata[w][l][j] = acc[j];
  __syncthreads();

  const int r = tid >> 2;
  const int jg = (tid & 3) * 4;
  float4 o;
  o.x = sdata[0][r][jg + 0] + sdata[1][r][jg + 0] + sdata[2][r][jg + 0] + sdata[3][r][jg + 0];
  o.y = sdata[0][r][jg + 1] + sdata[1][r][jg + 1] + sdata[2][r][jg + 1] + sdata[3][r][jg + 1];
  o.z = sdata[0][r][jg + 2] + sdata[1][r][jg + 2] + sdata[2][r][jg + 2] + sdata[3][r][jg + 2];
  o.w = sdata[0][r][jg + 3] + sdata[1][r][jg + 3] + sdata[2][r][jg + 3] + sdata[3][r][jg + 3];
  *(float4*)(h1 + ((size_t)blockIdx.x * 64 + r) * 16 + jg) = o;
}

// ================= gather layer 1: agg(h1) -> relu -> @W2 -> h2 =================
// wave per node; lane = (slot=l>>4, f=l&15); 4 edges/iter, 64B coalesced gather per edge
__global__ __launch_bounds__(256) void kgather1(const float* __restrict__ h1, const int* __restrict__ rs,
                                                const int* __restrict__ cnt, const int* __restrict__ csr_src,
                                                const float* __restrict__ csr_w, const float* __restrict__ dinv,
                                                const float* __restrict__ W2, const float* __restrict__ b1,
                                                float* __restrict__ h2) {
  __shared__ float sh_t[4][16];
  const int tid = threadIdx.x, wv = tid >> 6, l = tid & 63;
  const int n = blockIdx.x * 4 + wv;
  const int f = l & 15, slot = l >> 4;
  const int beg = rs[n], len = cnt[n];
  float acc = 0.f;
  for (int j = slot; j < len; j += 4) {
    int s = csr_src[beg + j];
    float w = csr_w[beg + j];
    acc = fmaf(w, h1[(size_t)s * 16 + f], acc);
  }
  acc += __shfl_xor(acc, 16, 64);
  acc += __shfl_xor(acc, 32, 64);
  if (slot == 0) {
    float dn = dinv[n];
    float t = dn * acc + dn * dn * h1[(size_t)n * 16 + f] + b1[f];
    sh_t[wv][f] = t > 0.f ? t : 0.f;
  }
  __syncthreads();
  if (tid < 16) {
    const int w2 = tid >> 2, c = tid & 3;
    const int nn = blockIdx.x * 4 + w2;
    float s = 0.f;
#pragma unroll
    for (int ff = 0; ff < 16; ++ff) s = fmaf(sh_t[w2][ff], W2[ff * 4 + c], s);
    h2[(size_t)nn * 4 + c] = s;
  }
}

// ================= gather layer 2: agg(h2) -> relu -> @W3 -> h3 =================
__global__ __launch_bounds__(256) void kgather2(const float* __restrict__ h2, const int* __restrict__ rs,
                                                const int* __restrict__ cnt, const int* __restrict__ csr_src,
                                                const float* __restrict__ csr_w, const float* __restrict__ dinv,
                                                const float* __restrict__ W3, const float* __restrict__ b2,
                                                float* __restrict__ h3) {
  const int tid = threadIdx.x, wv = tid >> 6, l = tid & 63;
  const int n = blockIdx.x * 4 + wv;
  const int f = l & 3, slot = l >> 2;
  const int beg = rs[n], len = cnt[n];
  float acc = 0.f;
  for (int j = slot; j < len; j += 16) {
    int s = csr_src[beg + j];
    float w = csr_w[beg + j];
    acc = fmaf(w, h2[(size_t)s * 4 + f], acc);
  }
#pragma unroll
  for (int off = 4; off < 64; off <<= 1) acc += __shfl_xor(acc, off, 64);
  const float dn = dinv[n];
  float t = dn * acc + dn * dn * h2[(size_t)n * 4 + f] + b2[f];
  t = t > 0.f ? t : 0.f;
  float p = t * W3[f];
  p += __shfl_xor(p, 1, 64);
  p += __shfl_xor(p, 2, 64);
  if (l == 0) h3[n] = p;
}

// ================= gather layer 3: agg(h3) -> relu -> flat =================
__global__ __launch_bounds__(256) void kgather3(const float* __restrict__ h3, const int* __restrict__ rs,
                                                const int* __restrict__ cnt, const int* __restrict__ csr_src,
                                                const float* __restrict__ csr_w, const float* __restrict__ dinv,
                                                const float* __restrict__ b3, float* __restrict__ flat) {
  const int tid = threadIdx.x, wv = tid >> 6, l = tid & 63;
  const int n = blockIdx.x * 4 + wv;
  const int beg = rs[n], len = cnt[n];
  float acc = 0.f;
  for (int j = l; j < len; j += 64) {
    int s = csr_src[beg + j];
    acc = fmaf(csr_w[beg + j], h3[s], acc);
  }
#pragma unroll
  for (int off = 1; off < 64; off <<= 1) acc += __shfl_xor(acc, off, 64);
  if (l == 0) {
    float dn = dinv[n];
    float t = dn * acc + dn * dn * h3[n] + b3[0];
    flat[n] = t > 0.f ? t : 0.f;
  }
}

// ================= out[b] = dot(flat, W_out[b,:]) + b_out[b] =================
__global__ __launch_bounds__(256) void kfinal(const float* __restrict__ flat, const float* __restrict__ Wout,
                                              const float* __restrict__ bout, float* __restrict__ out) {
  int b = blockIdx.x;
  const float4* __restrict__ f4 = (const float4*)flat;
  const float4* __restrict__ w4 = (const float4*)(Wout + (size_t)b * NNODES);
  float s = 0.f;
  for (int i = threadIdx.x; i < NNODES / 4; i += 256) {
    float4 a = f4[i];
    float4 wv = w4[i];
    s += a.x * wv.x + a.y * wv.y + a.z * wv.z + a.w * wv.w;
  }
#pragma unroll
  for (int off = 32; off; off >>= 1) s += __shfl_down(s, off, 64);
  __shared__ float red[4];
  if ((threadIdx.x & 63) == 0) red[threadIdx.x >> 6] = s;
  __syncthreads();
  if (threadIdx.x == 0) out[b] = red[0] + red[1] + red[2] + red[3] + bout[b];
}

extern "C" void kernel_launch(void* const* d_in, const int* in_sizes, int n_in,
                              void* d_out, int out_size, void* d_ws, size_t ws_size,
                              hipStream_t stream) {
  const float* x   = (const float*)d_in[0];
  const int*   A   = (const int*)d_in[1];
  const float* ew  = (const float*)d_in[2];
  const float* W1  = (const float*)d_in[3];
  const float* b1  = (const float*)d_in[4];
  const float* W2  = (const float*)d_in[5];
  const float* b2  = (const float*)d_in[6];
  const float* W3  = (const float*)d_in[7];
  const float* b3  = (const float*)d_in[8];
  const float* Wo  = (const float*)d_in[9];
  const float* bo  = (const float*)d_in[10];
  float* out = (float*)d_out;

  const int* src = A;
  const int* dst = A + NEDGES;

  // ---- workspace layout (4B words) ----
  char* p = (char*)d_ws;
  float* dinv    = (float*)p; p += sizeof(float) * NNODES;
  int*   cnt     = (int*)p;   p += sizeof(int) * NNODES;
  int*   rsofs   = (int*)p;   p += sizeof(int) * NNODES;
  int*   cursor  = (int*)p;   p += sizeof(int) * NNODES;
  int*   bsum    = (int*)p;   p += sizeof(int) * 256;
  int*   boff    = (int*)p;   p += sizeof(int) * 256;
  int*   csr_src = (int*)p;   p += sizeof(int) * NEDGES;
  float* csr_w   = (float*)p; p += sizeof(float) * NEDGES;
  float* h1      = (float*)p; p += sizeof(float) * (size_t)NNODES * 16;
  float* h2      = (float*)p; p += sizeof(float) * (size_t)NNODES * 4;
  float* h3      = (float*)p; p += sizeof(float) * NNODES;
  float* flat    = (float*)p; p += sizeof(float) * NNODES;

  // ---- CSR build ----
  kzerocnt<<<NNODES / 256, 256, 0, stream>>>(cnt);
  kcount<<<NEDGES / 256, 256, 0, stream>>>(dst, cnt);
  kscan1<<<NNODES / 256, 256, 0, stream>>>(cnt, rsofs, bsum);
  kscan2<<<1, 256, 0, stream>>>(bsum, boff);
  kscan3<<<NNODES / 256, 256, 0, stream>>>(rsofs, boff, cursor);
  kscatter<<<NEDGES / 256, 256, 0, stream>>>(src, dst, ew, cursor, csr_src, csr_w);
  kdeg<<<NNODES / 4, 256, 0, stream>>>(rsofs, cnt, csr_w, dinv);
  kwnorm<<<NEDGES / 256, 256, 0, stream>>>(csr_src, dinv, csr_w);

  // ---- network ----
  kgemm1<<<NNODES / 64, 256, 0, stream>>>(x, W1, h1);
  kgather1<<<NNODES / 4, 256, 0, stream>>>(h1, rsofs, cnt, csr_src, csr_w, dinv, W2, b1, h2);
  kgather2<<<NNODES / 4, 256, 0, stream>>>(h2, rsofs, cnt, csr_src, csr_w, dinv, W3, b2, h3);
  kgather3<<<NNODES / 4, 256, 0, stream>>>(h3, rsofs, cnt, csr_src, csr_w, dinv, b3, flat);
  kfinal<<<NB, 256, 0, stream>>>(flat, Wo, bo, out);
}

// Round 3
// 290.333 us; speedup vs baseline: 8.4516x; 1.5910x over previous
//
#include <hip/hip_runtime.h>

#define NNODES 65536
#define FIN 1024
#define NEDGES 2097152
#define NB 64
#define G 256                 // blocks in hist/scatter passes
#define CH (NEDGES / G)       // 8192 edges per block

// ================= pass 1: coarse histogram (dst>>8) per block =================
__global__ __launch_bounds__(256) void khist(const int* __restrict__ dst, int* __restrict__ counts) {
  __shared__ int hist[256];
  const int t = threadIdx.x, blk = blockIdx.x;
  hist[t] = 0;
  __syncthreads();
  const int base = blk * CH;
  for (int i = t; i < CH; i += 256) atomicAdd(&hist[dst[base + i] >> 8], 1);
  __syncthreads();
  counts[t * G + blk] = hist[t];            // bucket-major, block-minor
}

// ================= exclusive scan over 65536 cells (3 tiny kernels) =================
__global__ __launch_bounds__(256) void kscanA(const int* __restrict__ in, int* __restrict__ out,
                                              int* __restrict__ bsum) {
  __shared__ int sh[256];
  const int t = threadIdx.x, i = blockIdx.x * 256 + t;
  const int v = in[i];
  sh[t] = v;
  __syncthreads();
#pragma unroll
  for (int off = 1; off < 256; off <<= 1) {
    int a = (t >= off) ? sh[t - off] : 0;
    __syncthreads();
    sh[t] += a;
    __syncthreads();
  }
  out[i] = sh[t] - v;
  if (t == 255) bsum[blockIdx.x] = sh[255];
}

__global__ __launch_bounds__(256) void kscanB(int* __restrict__ bsum) {   // in-place exclusive
  __shared__ int sh[256];
  const int t = threadIdx.x;
  const int v = bsum[t];
  sh[t] = v;
  __syncthreads();
#pragma unroll
  for (int off = 1; off < 256; off <<= 1) {
    int a = (t >= off) ? sh[t - off] : 0;
    __syncthreads();
    sh[t] += a;
    __syncthreads();
  }
  bsum[t] = sh[t] - v;
}

__global__ __launch_bounds__(256) void kscanC(int* __restrict__ out, const int* __restrict__ bsum) {
  const int i = blockIdx.x * 256 + threadIdx.x;
  out[i] += bsum[blockIdx.x];
}

// ================= pass 2: scatter into bucket-grouped tmp (LDS cursors, no global atomics) ===
__global__ __launch_bounds__(256) void kscatter2(const int* __restrict__ src, const int* __restrict__ dst,
                                                 const float* __restrict__ ew, const int* __restrict__ ofs,
                                                 int2* __restrict__ tmp) {
  __shared__ int cursor[256];
  const int t = threadIdx.x, blk = blockIdx.x;
  cursor[t] = ofs[t * G + blk];
  __syncthreads();
  const int base = blk * CH;
  for (int i = t; i < CH; i += 256) {
    const int e = base + i;
    const int d = dst[e];
    const int s = src[e];
    const float w = ew[e];
    const int pos = atomicAdd(&cursor[d >> 8], 1);
    tmp[pos] = make_int2(s | ((d & 255) << 16), __float_as_int(w));
  }
}

// ================= pass 3: per-bucket fine sort + row starts/counts + dinv ==============
__global__ __launch_bounds__(256) void ksort(const int2* __restrict__ tmp, const int* __restrict__ ofs,
                                             int2* __restrict__ csr, int* __restrict__ rs,
                                             int* __restrict__ cnt, float* __restrict__ dinv) {
  __shared__ int hist[256];
  __shared__ int cursor[256];
  __shared__ int sh[256];
  __shared__ float degacc[256];
  const int t = threadIdx.x, b = blockIdx.x;
  const int base = ofs[b * G];
  const int end = (b == 255) ? NEDGES : ofs[(b + 1) * G];
  const int n = end - base;
  hist[t] = 0;
  degacc[t] = 0.f;
  __syncthreads();
  for (int i = t; i < n; i += 256) {
    int2 p = tmp[base + i];
    atomicAdd(&hist[(p.x >> 16) & 255], 1);
  }
  __syncthreads();
  const int v = hist[t];
  sh[t] = v;
  __syncthreads();
#pragma unroll
  for (int off = 1; off < 256; off <<= 1) {
    int a = (t >= off) ? sh[t - off] : 0;
    __syncthreads();
    sh[t] += a;
    __syncthreads();
  }
  const int excl = sh[t] - v;
  cursor[t] = excl;
  rs[b * 256 + t] = base + excl;
  cnt[b * 256 + t] = v;
  __syncthreads();
  for (int i = t; i < n; i += 256) {        // second read hits same-XCD L2 (96KB region)
    int2 p = tmp[base + i];
    const int fine = (p.x >> 16) & 255;
    const int pos = atomicAdd(&cursor[fine], 1);
    csr[base + pos] = make_int2(p.x & 0xFFFF, p.y);
    atomicAdd(&degacc[fine], __int_as_float(p.y));
  }
  __syncthreads();
  dinv[b * 256 + t] = rsqrtf(1.0f + degacc[t]);
}

// ================= fold source-side norm into weights (reused 3x) =================
__global__ __launch_bounds__(256) void kwnorm(int2* __restrict__ csr, const float* __restrict__ dinv) {
  const int j = blockIdx.x * 256 + threadIdx.x;
  int2 p = csr[j];
  p.y = __float_as_int(__int_as_float(p.y) * dinv[p.x]);
  csr[j] = p;
}

// ================= h1 = x @ W1  (65536x1024 @ 1024x16) =================
__global__ __launch_bounds__(256) void kgemm1(const float* __restrict__ x, const float* __restrict__ W1,
                                              float* __restrict__ h1) {
  __shared__ float sdata[4][64][16];
  const int tid = threadIdx.x;
  const int w = tid >> 6;
  const int l = tid & 63;
  const int row = blockIdx.x * 64 + l;
  const int wq = __builtin_amdgcn_readfirstlane(w);
  const float4* __restrict__ xr = (const float4*)(x + (size_t)row * FIN + (size_t)wq * 256);
  const float* __restrict__ Wq = W1 + (size_t)wq * 256 * 16;

  float acc[16];
#pragma unroll
  for (int j = 0; j < 16; ++j) acc[j] = 0.f;

  for (int k16 = 0; k16 < 16; ++k16) {
#pragma unroll
    for (int u = 0; u < 4; ++u) {
      const int k4 = k16 * 4 + u;
      float4 xv = xr[k4];
      const float xs[4] = {xv.x, xv.y, xv.z, xv.w};
#pragma unroll
      for (int i = 0; i < 4; ++i) {
        const float* __restrict__ wr = Wq + (k4 * 4 + i) * 16;
#pragma unroll
        for (int j = 0; j < 16; ++j) acc[j] = fmaf(xs[i], wr[j], acc[j]);
      }
    }
  }

#pragma unroll
  for (int j = 0; j < 16; ++j) sdata[w][l][j] = acc[j];
  __syncthreads();

  const int r = tid >> 2;
  const int jg = (tid & 3) * 4;
  float4 o;
  o.x = sdata[0][r][jg + 0] + sdata[1][r][jg + 0] + sdata[2][r][jg + 0] + sdata[3][r][jg + 0];
  o.y = sdata[0][r][jg + 1] + sdata[1][r][jg + 1] + sdata[2][r][jg + 1] + sdata[3][r][jg + 1];
  o.z = sdata[0][r][jg + 2] + sdata[1][r][jg + 2] + sdata[2][r][jg + 2] + sdata[3][r][jg + 2];
  o.w = sdata[0][r][jg + 3] + sdata[1][r][jg + 3] + sdata[2][r][jg + 3] + sdata[3][r][jg + 3];
  *(float4*)(h1 + ((size_t)blockIdx.x * 64 + r) * 16 + jg) = o;
}

// ================= gather layer 1: agg(h1) -> relu -> @W2 -> h2 =================
__global__ __launch_bounds__(256) void kgather1(const float* __restrict__ h1, const int* __restrict__ rs,
                                                const int* __restrict__ cnt, const int2* __restrict__ csr,
                                                const float* __restrict__ dinv,
                                                const float* __restrict__ W2, const float* __restrict__ b1,
                                                float* __restrict__ h2) {
  __shared__ float sh_t[4][16];
  const int tid = threadIdx.x, wv = tid >> 6, l = tid & 63;
  const int n = blockIdx.x * 4 + wv;
  const int f = l & 15, slot = l >> 4;
  const int beg = rs[n], len = cnt[n];
  float acc = 0.f;
  for (int j = slot; j < len; j += 4) {
    int2 p = csr[beg + j];
    acc = fmaf(__int_as_float(p.y), h1[(size_t)p.x * 16 + f], acc);
  }
  acc += __shfl_xor(acc, 16, 64);
  acc += __shfl_xor(acc, 32, 64);
  if (slot == 0) {
    float dn = dinv[n];
    float t = dn * acc + dn * dn * h1[(size_t)n * 16 + f] + b1[f];
    sh_t[wv][f] = t > 0.f ? t : 0.f;
  }
  __syncthreads();
  if (tid < 16) {
    const int w2 = tid >> 2, c = tid & 3;
    const int nn = blockIdx.x * 4 + w2;
    float s = 0.f;
#pragma unroll
    for (int ff = 0; ff < 16; ++ff) s = fmaf(sh_t[w2][ff], W2[ff * 4 + c], s);
    h2[(size_t)nn * 4 + c] = s;
  }
}

// ================= gather layer 2: agg(h2) -> relu -> @W3 -> h3 =================
__global__ __launch_bounds__(256) void kgather2(const float* __restrict__ h2, const int* __restrict__ rs,
                                                const int* __restrict__ cnt, const int2* __restrict__ csr,
                                                const float* __restrict__ dinv,
                                                const float* __restrict__ W3, const float* __restrict__ b2,
                                                float* __restrict__ h3) {
  const int tid = threadIdx.x, wv = tid >> 6, l = tid & 63;
  const int n = blockIdx.x * 4 + wv;
  const int f = l & 3, slot = l >> 2;
  const int beg = rs[n], len = cnt[n];
  float acc = 0.f;
  for (int j = slot; j < len; j += 16) {
    int2 p = csr[beg + j];
    acc = fmaf(__int_as_float(p.y), h2[(size_t)p.x * 4 + f], acc);
  }
#pragma unroll
  for (int off = 4; off < 64; off <<= 1) acc += __shfl_xor(acc, off, 64);
  const float dn = dinv[n];
  float t = dn * acc + dn * dn * h2[(size_t)n * 4 + f] + b2[f];
  t = t > 0.f ? t : 0.f;
  float p = t * W3[f];
  p += __shfl_xor(p, 1, 64);
  p += __shfl_xor(p, 2, 64);
  if (l == 0) h3[n] = p;
}

// ================= gather layer 3: agg(h3) -> relu -> flat =================
__global__ __launch_bounds__(256) void kgather3(const float* __restrict__ h3, const int* __restrict__ rs,
                                                const int* __restrict__ cnt, const int2* __restrict__ csr,
                                                const float* __restrict__ dinv,
                                                const float* __restrict__ b3, float* __restrict__ flat) {
  const int tid = threadIdx.x, wv = tid >> 6, l = tid & 63;
  const int n = blockIdx.x * 4 + wv;
  const int beg = rs[n], len = cnt[n];
  float acc = 0.f;
  for (int j = l; j < len; j += 64) {
    int2 p = csr[beg + j];
    acc = fmaf(__int_as_float(p.y), h3[p.x], acc);
  }
#pragma unroll
  for (int off = 1; off < 64; off <<= 1) acc += __shfl_xor(acc, off, 64);
  if (l == 0) {
    float dn = dinv[n];
    float t = dn * acc + dn * dn * h3[n] + b3[0];
    flat[n] = t > 0.f ? t : 0.f;
  }
}

// ================= out[b] = dot(flat, W_out[b,:]) + b_out[b] =================
__global__ __launch_bounds__(256) void kfinal(const float* __restrict__ flat, const float* __restrict__ Wout,
                                              const float* __restrict__ bout, float* __restrict__ out) {
  int b = blockIdx.x;
  const float4* __restrict__ f4 = (const float4*)flat;
  const float4* __restrict__ w4 = (const float4*)(Wout + (size_t)b * NNODES);
  float s = 0.f;
  for (int i = threadIdx.x; i < NNODES / 4; i += 256) {
    float4 a = f4[i];
    float4 wv = w4[i];
    s += a.x * wv.x + a.y * wv.y + a.z * wv.z + a.w * wv.w;
  }
#pragma unroll
  for (int off = 32; off; off >>= 1) s += __shfl_down(s, off, 64);
  __shared__ float red[4];
  if ((threadIdx.x & 63) == 0) red[threadIdx.x >> 6] = s;
  __syncthreads();
  if (threadIdx.x == 0) out[b] = red[0] + red[1] + red[2] + red[3] + bout[b];
}

extern "C" void kernel_launch(void* const* d_in, const int* in_sizes, int n_in,
                              void* d_out, int out_size, void* d_ws, size_t ws_size,
                              hipStream_t stream) {
  const float* x   = (const float*)d_in[0];
  const int*   A   = (const int*)d_in[1];
  const float* ew  = (const float*)d_in[2];
  const float* W1  = (const float*)d_in[3];
  const float* b1  = (const float*)d_in[4];
  const float* W2  = (const float*)d_in[5];
  const float* b2  = (const float*)d_in[6];
  const float* W3  = (const float*)d_in[7];
  const float* b3  = (const float*)d_in[8];
  const float* Wo  = (const float*)d_in[9];
  const float* bo  = (const float*)d_in[10];
  float* out = (float*)d_out;

  const int* src = A;
  const int* dst = A + NEDGES;

  // ---- workspace layout ----
  char* p = (char*)d_ws;
  float* dinv   = (float*)p; p += sizeof(float) * NNODES;
  int*   rsofs  = (int*)p;   p += sizeof(int) * NNODES;
  int*   cnt    = (int*)p;   p += sizeof(int) * NNODES;
  int*   counts = (int*)p;   p += sizeof(int) * 256 * G;      // (bucket, block)
  int*   ofs    = (int*)p;   p += sizeof(int) * 256 * G;
  int*   bsum   = (int*)p;   p += sizeof(int) * 256;
  int2*  tmp    = (int2*)p;  p += sizeof(int2) * NEDGES;
  int2*  csr    = (int2*)p;  p += sizeof(int2) * NEDGES;
  float* h1     = (float*)p; p += sizeof(float) * (size_t)NNODES * 16;
  float* h2     = (float*)p; p += sizeof(float) * (size_t)NNODES * 4;
  float* h3     = (float*)p; p += sizeof(float) * NNODES;
  float* flat   = (float*)p; p += sizeof(float) * NNODES;

  // ---- CSR build (no global atomics) ----
  khist<<<G, 256, 0, stream>>>(dst, counts);
  kscanA<<<256, 256, 0, stream>>>(counts, ofs, bsum);
  kscanB<<<1, 256, 0, stream>>>(bsum);
  kscanC<<<256, 256, 0, stream>>>(ofs, bsum);
  kscatter2<<<G, 256, 0, stream>>>(src, dst, ew, ofs, tmp);
  ksort<<<256, 256, 0, stream>>>(tmp, ofs, csr, rsofs, cnt, dinv);
  kwnorm<<<NEDGES / 256, 256, 0, stream>>>(csr, dinv);

  // ---- network ----
  kgemm1<<<NNODES / 64, 256, 0, stream>>>(x, W1, h1);
  kgather1<<<NNODES / 4, 256, 0, stream>>>(h1, rsofs, cnt, csr, dinv, W2, b1, h2);
  kgather2<<<NNODES / 4, 256, 0, stream>>>(h2, rsofs, cnt, csr, dinv, W3, b2, h3);
  kgather3<<<NNODES / 4, 256, 0, stream>>>(h3, rsofs, cnt, csr, dinv, b3, flat);
  kfinal<<<NB, 256, 0, stream>>>(flat, Wo, bo, out);
}